// Round 16
// baseline (389.226 us; speedup 1.0000x reference)
//
#include <hip/hip_runtime.h>
#include <cstddef>

#define NP 100000
#define NC 20000
#define NE 2000000
#define DIM 128
#define HID 128
#define OUTD 64

#define PBK 98      // ceil(NP/1024) buckets of 1024 providers
#define CBK 79      // ceil(NC/256)  buckets of 256 codes
#define CHUNK 4096  // edges per part-block

typedef __attribute__((ext_vector_type(8))) short short8v;
typedef __attribute__((ext_vector_type(4))) float f32x4;

__device__ __forceinline__ unsigned f2bf(float f) {
    unsigned u = __float_as_uint(f);
    return (u + 0x7FFFu + ((u >> 16) & 1u)) >> 16;   // RNE
}
__device__ __forceinline__ float bf2f(unsigned s) {
    return __uint_as_float(s << 16);
}

// ---------------- zero (bucket histograms only) ----------------
__global__ void zero4_kernel(float4* p, size_t n4) {
    size_t i = blockIdx.x * (size_t)blockDim.x + threadIdx.x;
    size_t stride = (size_t)gridDim.x * blockDim.x;
    float4 z = make_float4(0.f, 0.f, 0.f, 0.f);
    for (; i < n4; i += stride) p[i] = z;
}

// ---------------- f32 -> bf16 conversion ----------------
__global__ void conv_kernel(const float4* __restrict__ in, uint2* __restrict__ outp, size_t n4) {
    size_t i = blockIdx.x * (size_t)blockDim.x + threadIdx.x;
    size_t st = (size_t)gridDim.x * blockDim.x;
    for (; i < n4; i += st) {
        float4 v = in[i];
        outp[i] = make_uint2(f2bf(v.x) | (f2bf(v.y) << 16),
                             f2bf(v.z) | (f2bf(v.w) << 16));
    }
}

// ---------------- prepack weights into MFMA A-fragment order ----------------
__device__ __forceinline__ void pack_one(const float* __restrict__ w, unsigned short* __restrict__ dst,
                                         int M, int KT, int idx) {
    int lane = idx & 63;
    int rest = idx >> 6;
    int ks = rest % KT;
    int mt = rest / KT;
    int m  = mt * 16 + (lane & 15);
    int kb = ks * 32 + ((lane >> 4) << 3);
    uint4 r;
    r.x = f2bf(w[(kb + 0) * M + m]) | (f2bf(w[(kb + 1) * M + m]) << 16);
    r.y = f2bf(w[(kb + 2) * M + m]) | (f2bf(w[(kb + 3) * M + m]) << 16);
    r.z = f2bf(w[(kb + 4) * M + m]) | (f2bf(w[(kb + 5) * M + m]) << 16);
    r.w = f2bf(w[(kb + 6) * M + m]) | (f2bf(w[(kb + 7) * M + m]) << 16);
    *(uint4*)(dst + (size_t)idx * 8) = r;
}
__global__ __launch_bounds__(256) void pack_kernel(
    const float* __restrict__ w1p, const float* __restrict__ w2p,
    const float* __restrict__ w1c, const float* __restrict__ w2c,
    unsigned short* __restrict__ d1p, unsigned short* __restrict__ d2p,
    unsigned short* __restrict__ d1c, unsigned short* __restrict__ d2c) {
    int idx = blockIdx.x * 256 + threadIdx.x;     // 0..10239
    if (idx < 4096)       pack_one(w1p, d1p, 128, 8, idx);
    else if (idx < 5120)  pack_one(w2p, d2p, 64, 4, idx - 4096);
    else if (idx < 9216)  pack_one(w1c, d1c, 128, 8, idx - 5120);
    else if (idx < 10240) pack_one(w2c, d2c, 64, 4, idx - 9216);
}

// ---------------- bucket histogram ----------------
__global__ __launch_bounds__(256) void bhist_kernel(
    const int* __restrict__ ep, const int* __restrict__ ec,
    int* __restrict__ PH, int* __restrict__ CH)
{
    __shared__ int hp[PBK];
    __shared__ int hc[CBK];
    int t = threadIdx.x;
    if (t < PBK) hp[t] = 0;
    if (t < CBK) hc[t] = 0;
    __syncthreads();
    for (int e = blockIdx.x * 256 + t; e < NE; e += 256 * 256) {
        atomicAdd(&hp[ep[e] >> 10], 1);
        atomicAdd(&hc[ec[e] >> 8], 1);
    }
    __syncthreads();
    if (t < PBK) atomicAdd(&PH[t * 16], hp[t]);
    if (t < CBK) atomicAdd(&CH[t * 16], hc[t]);
}

// ---------------- bucket scans ----------------
__global__ __launch_bounds__(256) void bscan_kernel(
    const int* __restrict__ PH, const int* __restrict__ CH,
    int* __restrict__ POFF, int* __restrict__ COFF,
    int* __restrict__ PCUR, int* __restrict__ CCUR)
{
    __shared__ int s[256];
    int t = threadIdx.x;
    s[t] = (t < PBK) ? PH[t * 16] : 0;
    __syncthreads();
    for (int off = 1; off < 256; off <<= 1) {
        int a = (t >= off) ? s[t - off] : 0;
        __syncthreads();
        s[t] += a;
        __syncthreads();
    }
    int excl = t ? s[t - 1] : 0;
    if (t < PBK) { POFF[t] = excl; PCUR[t * 16] = excl; }
    if (t == 0) POFF[PBK] = NE;
    __syncthreads();
    s[t] = (t < CBK) ? CH[t * 16] : 0;
    __syncthreads();
    for (int off = 1; off < 256; off <<= 1) {
        int a = (t >= off) ? s[t - off] : 0;
        __syncthreads();
        s[t] += a;
        __syncthreads();
    }
    excl = t ? s[t - 1] : 0;
    if (t < CBK) { COFF[t] = excl; CCUR[t * 16] = excl; }
    if (t == 0) COFF[CBK] = NE;
}

// ---------------- pass A: partition into buckets ----------------
// P record: ((p&1023)<<15)|c ; C record: ((c&255)<<17)|p ; .y = w * 2^21 (float bits).
// w*2^21 is an exact exponent shift, so agg's (int)(ws*e) is bit-identical to
// the previous (int)(w*e*2^21) — same output bits, 3 fewer VALU ops per edge.
__global__ __launch_bounds__(256) void part_kernel(
    const int* __restrict__ ep, const int* __restrict__ ec, const float* __restrict__ ew,
    int* __restrict__ PCUR, int* __restrict__ CCUR,
    uint2* __restrict__ Ap, uint2* __restrict__ Ac)
{
    __shared__ int cp[PBK], bp_[PBK], cc[CBK], bc_[CBK];
    int t = threadIdx.x;
    int base = blockIdx.x * CHUNK;
    if (t < PBK) cp[t] = 0;
    if (t < CBK) cc[t] = 0;
    __syncthreads();
    #pragma unroll
    for (int i = 0; i < CHUNK / 256; ++i) {
        int e = base + i * 256 + t;
        if (e < NE) {
            atomicAdd(&cp[ep[e] >> 10], 1);
            atomicAdd(&cc[ec[e] >> 8], 1);
        }
    }
    __syncthreads();
    if (t < PBK) { bp_[t] = atomicAdd(&PCUR[t * 16], cp[t]); cp[t] = 0; }
    if (t < CBK) { bc_[t] = atomicAdd(&CCUR[t * 16], cc[t]); cc[t] = 0; }
    __syncthreads();
    #pragma unroll
    for (int i = 0; i < CHUNK / 256; ++i) {
        int e = base + i * 256 + t;
        if (e < NE) {
            unsigned p = (unsigned)ep[e];
            unsigned c = (unsigned)ec[e];
            unsigned wb = __float_as_uint(ew[e] * 2097152.0f);   // w * 2^21 (exact)
            int b1 = p >> 10;
            int pos = bp_[b1] + atomicAdd(&cp[b1], 1);
            Ap[pos] = make_uint2(((p & 1023u) << 15) | c, wb);
            int b2 = c >> 8;
            int pos2 = bc_[b2] + atomicAdd(&cc[b2], 1);
            Ac[pos2] = make_uint2(((c & 255u) << 17) | p, wb);
        }
    }
}

// ---------------- pass B: within-bucket counting sort + per-row CSR ----------------
template<int LOCALS, int SHIFT, unsigned NMASK>
__global__ __launch_bounds__(256) void bsort_kernel(
    const uint2* __restrict__ A, const int* __restrict__ OFF,
    int2* __restrict__ S, int* __restrict__ rowoff, int nrows_total, int nbins)
{
    __shared__ int cnt[LOCALS];
    __shared__ int tsum[256];
    constexpr int NL = LOCALS / 256;
    int t = threadIdx.x;
    int b = blockIdx.x;
    int s0 = OFF[b], e0 = OFF[b + 1];
    #pragma unroll
    for (int k = 0; k < NL; ++k) cnt[t * NL + k] = 0;
    __syncthreads();
    for (int j = s0 + t; j < e0; j += 256)
        atomicAdd(&cnt[A[j].x >> SHIFT], 1);
    __syncthreads();
    int pre[NL];
    int run = 0;
    #pragma unroll
    for (int k = 0; k < NL; ++k) { pre[k] = run; run += cnt[t * NL + k]; }
    tsum[t] = run;
    __syncthreads();
    for (int off = 1; off < 256; off <<= 1) {
        int a = (t >= off) ? tsum[t - off] : 0;
        __syncthreads();
        tsum[t] += a;
        __syncthreads();
    }
    int excl = t ? tsum[t - 1] : 0;
    #pragma unroll
    for (int k = 0; k < NL; ++k) cnt[t * NL + k] = excl + pre[k];
    __syncthreads();
    int rowbase = b * LOCALS;
    #pragma unroll
    for (int k = 0; k < NL; ++k) {
        int r = t * NL + k;
        if (rowbase + r < nrows_total) rowoff[rowbase + r] = s0 + cnt[r];
    }
    if (b == nbins - 1 && t == 0) rowoff[nrows_total] = e0;
    __syncthreads();   // rowoff reads of cnt complete before scatter mutates cnt
    for (int j = s0 + t; j < e0; j += 256) {
        uint2 v = A[j];
        int loc = (int)(v.x >> SHIFT);
        int pos = s0 + atomicAdd(&cnt[loc], 1);
        S[pos] = make_int2((int)(v.x & NMASK), (int)v.y);
    }
}

// ---------------- aggregate: wave per row, bf16 gather, unroll x4 ----------------
// Fixed-point int32 accumulation (scale 2^21, w pre-scaled in part): integer
// sums are order-invariant, so the racy storage order upstream cannot change
// the output bit pattern between calls. Bounds: |emb| <= ~0.02, weighted
// degree <= ~300 -> |iacc| < 2^24, |ideg| < 2^30.
__global__ __launch_bounds__(256) void agg_kernel(
    const int2* __restrict__ sorted, const int* __restrict__ off,
    const unsigned short* __restrict__ nbremb_bf, unsigned short* __restrict__ msg_bf)
{
    const float ISCL = 1.0f / 2097152.0f;
    int wave = threadIdx.x >> 6;
    int lane = threadIdx.x & 63;
    int row = blockIdx.x * 4 + wave;   // grid sized exactly
    int start = off[row];
    int end   = off[row + 1];
    int iacc0 = 0, iacc1 = 0, ideg = 0;
    int j = start;
    for (; j + 4 <= end; j += 4) {
        int2 v0 = sorted[j];
        int2 v1 = sorted[j + 1];
        int2 v2 = sorted[j + 2];
        int2 v3 = sorted[j + 3];
        unsigned pk0 = *(const unsigned*)(nbremb_bf + (size_t)v0.x * DIM + 2 * lane);
        unsigned pk1 = *(const unsigned*)(nbremb_bf + (size_t)v1.x * DIM + 2 * lane);
        unsigned pk2 = *(const unsigned*)(nbremb_bf + (size_t)v2.x * DIM + 2 * lane);
        unsigned pk3 = *(const unsigned*)(nbremb_bf + (size_t)v3.x * DIM + 2 * lane);
        float w0 = __int_as_float(v0.y), w1 = __int_as_float(v1.y);
        float w2 = __int_as_float(v2.y), w3 = __int_as_float(v3.y);
        ideg  += (int)w0 + (int)w1 + (int)w2 + (int)w3;
        iacc0 += (int)(w0 * bf2f(pk0 & 0xFFFFu)) + (int)(w1 * bf2f(pk1 & 0xFFFFu))
               + (int)(w2 * bf2f(pk2 & 0xFFFFu)) + (int)(w3 * bf2f(pk3 & 0xFFFFu));
        iacc1 += (int)(w0 * bf2f(pk0 >> 16)) + (int)(w1 * bf2f(pk1 >> 16))
               + (int)(w2 * bf2f(pk2 >> 16)) + (int)(w3 * bf2f(pk3 >> 16));
    }
    for (; j < end; ++j) {
        int2 v = sorted[j];
        float w = __int_as_float(v.y);
        unsigned pk = *(const unsigned*)(nbremb_bf + (size_t)v.x * DIM + 2 * lane);
        ideg  += (int)w;
        iacc0 += (int)(w * bf2f(pk & 0xFFFFu));
        iacc1 += (int)(w * bf2f(pk >> 16));
    }
    float deg = (float)ideg * ISCL;
    float inv = 1.0f / (deg + 1e-8f);
    float a0 = (float)iacc0 * ISCL;
    float a1 = (float)iacc1 * ISCL;
    unsigned o = f2bf(a0 * inv) | (f2bf(a1 * inv) << 16);
    *(unsigned*)(msg_bf + (size_t)row * DIM + 2 * lane) = o;
}

// ---------------- MFMA MLP: swapped-operand, wave per 16 rows ----------------
// NOTE: the 32-row variant failed the harness determinism check 3/3 times
// (R8/R9/R15) while this 16-row variant passed 3/3 (R7/R10/R14). Mechanism
// unidentified; 16-row form is frozen.
#define HP 136   // hs row pitch in bf16
__global__ __launch_bounds__(256) void mlp_mfma_kernel(
    const unsigned short* __restrict__ embbf, const unsigned short* __restrict__ msgbf,
    const unsigned short* __restrict__ w1pk, const unsigned short* __restrict__ w2pk,
    const float* __restrict__ b1, const float* __restrict__ g1, const float* __restrict__ be1,
    const float* __restrict__ b2, const float* __restrict__ g2, const float* __restrict__ be2,
    float* __restrict__ out, int nrows)
{
    __shared__ __align__(16) unsigned short hs_all[4][16 * HP];
    int t = threadIdx.x;
    int wave = t >> 6, lane = t & 63;
    int tile = blockIdx.x * 4 + wave;
    if (tile * 16 >= nrows) return;          // padding waves only; no barriers used
    int r16 = lane & 15;
    int hi  = lane >> 4;
    int row = tile * 16 + r16;
    unsigned short* hs = hs_all[wave];

    // ---- layer 1: 8 mt x 8 ks MFMAs ----
    f32x4 acc[8];
    #pragma unroll
    for (int mt = 0; mt < 8; ++mt) {
        float4 bb = *(const float4*)&b1[mt * 16 + hi * 4];
        acc[mt] = (f32x4){bb.x, bb.y, bb.z, bb.w};
    }
    const unsigned short* x0 = embbf + (size_t)row * DIM;
    const unsigned short* x1 = msgbf + (size_t)row * DIM;
    #pragma unroll
    for (int ks = 0; ks < 8; ++ks) {
        const unsigned short* xs = (ks < 4) ? (x0 + ks * 32 + hi * 8)
                                            : (x1 + (ks - 4) * 32 + hi * 8);
        short8v bfrag = *(const short8v*)xs;
        #pragma unroll
        for (int mt = 0; mt < 8; ++mt) {
            short8v afrag = *(const short8v*)(w1pk + (((mt * 8 + ks) * 64 + lane) << 3));
            acc[mt] = __builtin_amdgcn_mfma_f32_16x16x32_bf16(afrag, bfrag, acc[mt], 0, 0, 0);
        }
    }

    // ---- LN1 + ReLU -> hs (bf16) ----
    float s = 0.f, q = 0.f;
    #pragma unroll
    for (int mt = 0; mt < 8; ++mt) {
        #pragma unroll
        for (int r = 0; r < 4; ++r) { float v = acc[mt][r]; s += v; q += v * v; }
    }
    s += __shfl_xor(s, 16); s += __shfl_xor(s, 32);
    q += __shfl_xor(q, 16); q += __shfl_xor(q, 32);
    float mu = s * (1.0f / 128.0f);
    float var = q * (1.0f / 128.0f) - mu * mu;
    float rstd = rsqrtf(var + 1e-5f);
    #pragma unroll
    for (int mt = 0; mt < 8; ++mt) {
        float4 gg = *(const float4*)&g1[mt * 16 + hi * 4];
        float4 bb = *(const float4*)&be1[mt * 16 + hi * 4];
        float h0 = fmaxf((acc[mt][0] - mu) * rstd * gg.x + bb.x, 0.f);
        float h1 = fmaxf((acc[mt][1] - mu) * rstd * gg.y + bb.y, 0.f);
        float h2 = fmaxf((acc[mt][2] - mu) * rstd * gg.z + bb.z, 0.f);
        float h3 = fmaxf((acc[mt][3] - mu) * rstd * gg.w + bb.w, 0.f);
        uint2 pk = make_uint2(f2bf(h0) | (f2bf(h1) << 16), f2bf(h2) | (f2bf(h3) << 16));
        *(uint2*)&hs[r16 * HP + mt * 16 + hi * 4] = pk;
    }

    // ---- layer 2: 4 mt x 4 ks MFMAs ----
    f32x4 acc2[4];
    #pragma unroll
    for (int mt = 0; mt < 4; ++mt) {
        float4 bb = *(const float4*)&b2[mt * 16 + hi * 4];
        acc2[mt] = (f32x4){bb.x, bb.y, bb.z, bb.w};
    }
    #pragma unroll
    for (int ks = 0; ks < 4; ++ks) {
        short8v bfrag = *(const short8v*)&hs[r16 * HP + ks * 32 + hi * 8];
        #pragma unroll
        for (int mt = 0; mt < 4; ++mt) {
            short8v afrag = *(const short8v*)(w2pk + (((mt * 4 + ks) * 64 + lane) << 3));
            acc2[mt] = __builtin_amdgcn_mfma_f32_16x16x32_bf16(afrag, bfrag, acc2[mt], 0, 0, 0);
        }
    }

    // ---- LN2 -> out ----
    float s2 = 0.f, q2 = 0.f;
    #pragma unroll
    for (int mt = 0; mt < 4; ++mt) {
        #pragma unroll
        for (int r = 0; r < 4; ++r) { float v = acc2[mt][r]; s2 += v; q2 += v * v; }
    }
    s2 += __shfl_xor(s2, 16); s2 += __shfl_xor(s2, 32);
    q2 += __shfl_xor(q2, 16); q2 += __shfl_xor(q2, 32);
    float mu2 = s2 * (1.0f / 64.0f);
    float var2 = q2 * (1.0f / 64.0f) - mu2 * mu2;
    float rstd2 = rsqrtf(var2 + 1e-5f);
    #pragma unroll
    for (int mt = 0; mt < 4; ++mt) {
        float4 gg = *(const float4*)&g2[mt * 16 + hi * 4];
        float4 bb = *(const float4*)&be2[mt * 16 + hi * 4];
        float4 o;
        o.x = (acc2[mt][0] - mu2) * rstd2 * gg.x + bb.x;
        o.y = (acc2[mt][1] - mu2) * rstd2 * gg.y + bb.y;
        o.z = (acc2[mt][2] - mu2) * rstd2 * gg.z + bb.z;
        o.w = (acc2[mt][3] - mu2) * rstd2 * gg.w + bb.w;
        *(float4*)&out[(size_t)row * OUTD + mt * 16 + hi * 4] = o;
    }
}

extern "C" void kernel_launch(void* const* d_in, const int* in_sizes, int n_in,
                              void* d_out, int out_size, void* d_ws, size_t ws_size,
                              hipStream_t stream) {
    const int*   ep   = (const int*)d_in[0];
    const int*   ec   = (const int*)d_in[1];
    const float* ew   = (const float*)d_in[2];
    const float* pemb = (const float*)d_in[3];
    const float* cemb = (const float*)d_in[4];
    const float* w1p  = (const float*)d_in[5];
    const float* b1p  = (const float*)d_in[6];
    const float* g1p  = (const float*)d_in[7];
    const float* be1p = (const float*)d_in[8];
    const float* w2p  = (const float*)d_in[9];
    const float* b2p  = (const float*)d_in[10];
    const float* g2p  = (const float*)d_in[11];
    const float* be2p = (const float*)d_in[12];
    const float* w1c  = (const float*)d_in[13];
    const float* b1c  = (const float*)d_in[14];
    const float* g1c  = (const float*)d_in[15];
    const float* be1c = (const float*)d_in[16];
    const float* w2c  = (const float*)d_in[17];
    const float* b2c  = (const float*)d_in[18];
    const float* g2c  = (const float*)d_in[19];
    const float* be2c = (const float*)d_in[20];

    // ---- meta workspace (ints) ----
    int* wsi  = (int*)d_ws;
    int* PH   = wsi;               // [98*16]  zeroed every call
    int* CH   = PH + 1568;         // [79*16]  zeroed every call
    int* PCUR = CH + 1264;         // [98*16]  (written by bscan)
    int* CCUR = PCUR + 1568;       // [79*16]
    int* POFF = CCUR + 1264;       // [100]
    int* COFF = POFF + 100;        // [84]
    int* rowoff_p = COFF + 84;         // [100004]
    int* rowoff_c = rowoff_p + 100004; // [20004]
    const int zero_ints = 1568 + 1264;                                      // 2832
    const int meta_ints = 2832 + 1568 + 1264 + 100 + 84 + 100004 + 20004;   // 125856

    // ---- big regions (stream-ordered lifetimes; aliases noted) ----
    char* big = (char*)(wsi + meta_ints);
    uint2* Ap = (uint2*)big;                             // 16 MB  (part out, bsort_p in)
    int2*  Sp = (int2*)(big + 16000000);                 // 16 MB  (bsort_p out, agg_p in)
    char*  zoneC = big + 32000000;                       // 30.72 MB zone
    uint2* Ac = (uint2*)zoneC;                           //   16 MB (part out, bsort_c in)
    int2*  Sc = (int2*)Ap;                               //   aliases Ap (dead after bsort_p)
    unsigned short* pmsgb = (unsigned short*)zoneC;                   // 25.6 MB (after bsort_c)
    unsigned short* cmsgb = (unsigned short*)(zoneC + 25600000);      // 5.12 MB
    unsigned short* pembbf = (unsigned short*)(zoneC + 30720000);     // 25.6 MB
    unsigned short* cembbf = pembbf + (size_t)NP * DIM;               // 5.12 MB
    unsigned short* w1pk_p = cembbf + (size_t)NC * DIM;  // 64 KB
    unsigned short* w2pk_p = w1pk_p + 32768;             // 16 KB
    unsigned short* w1pk_c = w2pk_p + 8192;              // 64 KB
    unsigned short* w2pk_c = w1pk_c + 32768;             // 16 KB

    zero4_kernel<<<3, 256, 0, stream>>>((float4*)wsi, (size_t)zero_ints / 4);

    // bf16 conversions + weight prepack (independent of edge pipeline)
    conv_kernel<<<2048, 256, 0, stream>>>((const float4*)pemb, (uint2*)pembbf,
                                          (size_t)NP * DIM / 4);
    conv_kernel<<<640, 256, 0, stream>>>((const float4*)cemb, (uint2*)cembbf,
                                         (size_t)NC * DIM / 4);
    pack_kernel<<<40, 256, 0, stream>>>(w1p, w2p, w1c, w2c,
                                        w1pk_p, w2pk_p, w1pk_c, w2pk_c);

    bhist_kernel<<<256, 256, 0, stream>>>(ep, ec, PH, CH);
    bscan_kernel<<<1, 256, 0, stream>>>(PH, CH, POFF, COFF, PCUR, CCUR);

    int pblocks = (NE + CHUNK - 1) / CHUNK;   // 489
    part_kernel<<<pblocks, 256, 0, stream>>>(ep, ec, ew, PCUR, CCUR, Ap, Ac);

    bsort_kernel<1024, 15, 0x7FFFu><<<PBK, 256, 0, stream>>>(Ap, POFF, Sp, rowoff_p, NP, PBK);
    bsort_kernel<256, 17, 0x1FFFFu><<<CBK, 256, 0, stream>>>(Ac, COFF, Sc, rowoff_c, NC, CBK);

    agg_kernel<<<NP / 4, 256, 0, stream>>>(Sp, rowoff_p, cembbf, pmsgb);
    agg_kernel<<<NC / 4, 256, 0, stream>>>(Sc, rowoff_c, pembbf, cmsgb);

    float* out_p = (float*)d_out;             // [NP, 64]
    float* out_c = out_p + (size_t)NP * OUTD; // [NC, 64]

    mlp_mfma_kernel<<<(NP / 16 + 3) / 4, 256, 0, stream>>>(
        pembbf, pmsgb, w1pk_p, w2pk_p,
        b1p, g1p, be1p, b2p, g2p, be2p, out_p, NP);
    mlp_mfma_kernel<<<(NC / 16 + 3) / 4, 256, 0, stream>>>(
        cembbf, cmsgb, w1pk_c, w2pk_c,
        b1c, g1c, be1c, b2c, g2c, be2c, out_c, NC);
}

// Round 17
// 381.795 us; speedup vs baseline: 1.0195x; 1.0195x over previous
//
#include <hip/hip_runtime.h>
#include <cstddef>

#define NP 100000
#define NC 20000
#define NE 2000000
#define DIM 128
#define HID 128
#define OUTD 64

#define PBK 98      // ceil(NP/1024) buckets of 1024 providers
#define CBK 79      // ceil(NC/256)  buckets of 256 codes
#define CHUNK 4096  // edges per part-block

typedef __attribute__((ext_vector_type(8))) short short8v;
typedef __attribute__((ext_vector_type(4))) float f32x4;

__device__ __forceinline__ unsigned f2bf(float f) {
    unsigned u = __float_as_uint(f);
    return (u + 0x7FFFu + ((u >> 16) & 1u)) >> 16;   // RNE
}
__device__ __forceinline__ float bf2f(unsigned s) {
    return __uint_as_float(s << 16);
}

// ---------------- zero (bucket histograms only) ----------------
__global__ void zero4_kernel(float4* p, size_t n4) {
    size_t i = blockIdx.x * (size_t)blockDim.x + threadIdx.x;
    size_t stride = (size_t)gridDim.x * blockDim.x;
    float4 z = make_float4(0.f, 0.f, 0.f, 0.f);
    for (; i < n4; i += stride) p[i] = z;
}

// ---------------- f32 -> bf16 conversion ----------------
__global__ void conv_kernel(const float4* __restrict__ in, uint2* __restrict__ outp, size_t n4) {
    size_t i = blockIdx.x * (size_t)blockDim.x + threadIdx.x;
    size_t st = (size_t)gridDim.x * blockDim.x;
    for (; i < n4; i += st) {
        float4 v = in[i];
        outp[i] = make_uint2(f2bf(v.x) | (f2bf(v.y) << 16),
                             f2bf(v.z) | (f2bf(v.w) << 16));
    }
}

// ---------------- prepack weights into MFMA A-fragment order ----------------
__device__ __forceinline__ void pack_one(const float* __restrict__ w, unsigned short* __restrict__ dst,
                                         int M, int KT, int idx) {
    int lane = idx & 63;
    int rest = idx >> 6;
    int ks = rest % KT;
    int mt = rest / KT;
    int m  = mt * 16 + (lane & 15);
    int kb = ks * 32 + ((lane >> 4) << 3);
    uint4 r;
    r.x = f2bf(w[(kb + 0) * M + m]) | (f2bf(w[(kb + 1) * M + m]) << 16);
    r.y = f2bf(w[(kb + 2) * M + m]) | (f2bf(w[(kb + 3) * M + m]) << 16);
    r.z = f2bf(w[(kb + 4) * M + m]) | (f2bf(w[(kb + 5) * M + m]) << 16);
    r.w = f2bf(w[(kb + 6) * M + m]) | (f2bf(w[(kb + 7) * M + m]) << 16);
    *(uint4*)(dst + (size_t)idx * 8) = r;
}
__global__ __launch_bounds__(256) void pack_kernel(
    const float* __restrict__ w1p, const float* __restrict__ w2p,
    const float* __restrict__ w1c, const float* __restrict__ w2c,
    unsigned short* __restrict__ d1p, unsigned short* __restrict__ d2p,
    unsigned short* __restrict__ d1c, unsigned short* __restrict__ d2c) {
    int idx = blockIdx.x * 256 + threadIdx.x;     // 0..10239
    if (idx < 4096)       pack_one(w1p, d1p, 128, 8, idx);
    else if (idx < 5120)  pack_one(w2p, d2p, 64, 4, idx - 4096);
    else if (idx < 9216)  pack_one(w1c, d1c, 128, 8, idx - 5120);
    else if (idx < 10240) pack_one(w2c, d2c, 64, 4, idx - 9216);
}

// ---------------- bucket histogram ----------------
__global__ __launch_bounds__(256) void bhist_kernel(
    const int* __restrict__ ep, const int* __restrict__ ec,
    int* __restrict__ PH, int* __restrict__ CH)
{
    __shared__ int hp[PBK];
    __shared__ int hc[CBK];
    int t = threadIdx.x;
    if (t < PBK) hp[t] = 0;
    if (t < CBK) hc[t] = 0;
    __syncthreads();
    for (int e = blockIdx.x * 256 + t; e < NE; e += 256 * 256) {
        atomicAdd(&hp[ep[e] >> 10], 1);
        atomicAdd(&hc[ec[e] >> 8], 1);
    }
    __syncthreads();
    if (t < PBK) atomicAdd(&PH[t * 16], hp[t]);
    if (t < CBK) atomicAdd(&CH[t * 16], hc[t]);
}

// ---------------- bucket scans ----------------
__global__ __launch_bounds__(256) void bscan_kernel(
    const int* __restrict__ PH, const int* __restrict__ CH,
    int* __restrict__ POFF, int* __restrict__ COFF,
    int* __restrict__ PCUR, int* __restrict__ CCUR)
{
    __shared__ int s[256];
    int t = threadIdx.x;
    s[t] = (t < PBK) ? PH[t * 16] : 0;
    __syncthreads();
    for (int off = 1; off < 256; off <<= 1) {
        int a = (t >= off) ? s[t - off] : 0;
        __syncthreads();
        s[t] += a;
        __syncthreads();
    }
    int excl = t ? s[t - 1] : 0;
    if (t < PBK) { POFF[t] = excl; PCUR[t * 16] = excl; }
    if (t == 0) POFF[PBK] = NE;
    __syncthreads();
    s[t] = (t < CBK) ? CH[t * 16] : 0;
    __syncthreads();
    for (int off = 1; off < 256; off <<= 1) {
        int a = (t >= off) ? s[t - off] : 0;
        __syncthreads();
        s[t] += a;
        __syncthreads();
    }
    excl = t ? s[t - 1] : 0;
    if (t < CBK) { COFF[t] = excl; CCUR[t * 16] = excl; }
    if (t == 0) COFF[CBK] = NE;
}

// ---------------- pass A: partition into buckets ----------------
// P record: ((p&1023)<<15)|c ; C record: ((c&255)<<17)|p ; .y = weight bits
__global__ __launch_bounds__(256) void part_kernel(
    const int* __restrict__ ep, const int* __restrict__ ec, const float* __restrict__ ew,
    int* __restrict__ PCUR, int* __restrict__ CCUR,
    uint2* __restrict__ Ap, uint2* __restrict__ Ac)
{
    __shared__ int cp[PBK], bp_[PBK], cc[CBK], bc_[CBK];
    int t = threadIdx.x;
    int base = blockIdx.x * CHUNK;
    if (t < PBK) cp[t] = 0;
    if (t < CBK) cc[t] = 0;
    __syncthreads();
    #pragma unroll
    for (int i = 0; i < CHUNK / 256; ++i) {
        int e = base + i * 256 + t;
        if (e < NE) {
            atomicAdd(&cp[ep[e] >> 10], 1);
            atomicAdd(&cc[ec[e] >> 8], 1);
        }
    }
    __syncthreads();
    if (t < PBK) { bp_[t] = atomicAdd(&PCUR[t * 16], cp[t]); cp[t] = 0; }
    if (t < CBK) { bc_[t] = atomicAdd(&CCUR[t * 16], cc[t]); cc[t] = 0; }
    __syncthreads();
    #pragma unroll
    for (int i = 0; i < CHUNK / 256; ++i) {
        int e = base + i * 256 + t;
        if (e < NE) {
            unsigned p = (unsigned)ep[e];
            unsigned c = (unsigned)ec[e];
            unsigned wb = __float_as_uint(ew[e]);
            int b1 = p >> 10;
            int pos = bp_[b1] + atomicAdd(&cp[b1], 1);
            Ap[pos] = make_uint2(((p & 1023u) << 15) | c, wb);
            int b2 = c >> 8;
            int pos2 = bc_[b2] + atomicAdd(&cc[b2], 1);
            Ac[pos2] = make_uint2(((c & 255u) << 17) | p, wb);
        }
    }
}

// ---------------- pass B: within-bucket counting sort + per-row CSR ----------------
template<int LOCALS, int SHIFT, unsigned NMASK>
__global__ __launch_bounds__(256) void bsort_kernel(
    const uint2* __restrict__ A, const int* __restrict__ OFF,
    int2* __restrict__ S, int* __restrict__ rowoff, int nrows_total, int nbins)
{
    __shared__ int cnt[LOCALS];
    __shared__ int tsum[256];
    constexpr int NL = LOCALS / 256;
    int t = threadIdx.x;
    int b = blockIdx.x;
    int s0 = OFF[b], e0 = OFF[b + 1];
    #pragma unroll
    for (int k = 0; k < NL; ++k) cnt[t * NL + k] = 0;
    __syncthreads();
    for (int j = s0 + t; j < e0; j += 256)
        atomicAdd(&cnt[A[j].x >> SHIFT], 1);
    __syncthreads();
    int pre[NL];
    int run = 0;
    #pragma unroll
    for (int k = 0; k < NL; ++k) { pre[k] = run; run += cnt[t * NL + k]; }
    tsum[t] = run;
    __syncthreads();
    for (int off = 1; off < 256; off <<= 1) {
        int a = (t >= off) ? tsum[t - off] : 0;
        __syncthreads();
        tsum[t] += a;
        __syncthreads();
    }
    int excl = t ? tsum[t - 1] : 0;
    #pragma unroll
    for (int k = 0; k < NL; ++k) cnt[t * NL + k] = excl + pre[k];
    __syncthreads();
    int rowbase = b * LOCALS;
    #pragma unroll
    for (int k = 0; k < NL; ++k) {
        int r = t * NL + k;
        if (rowbase + r < nrows_total) rowoff[rowbase + r] = s0 + cnt[r];
    }
    if (b == nbins - 1 && t == 0) rowoff[nrows_total] = e0;
    __syncthreads();   // rowoff reads of cnt complete before scatter mutates cnt
    for (int j = s0 + t; j < e0; j += 256) {
        uint2 v = A[j];
        int loc = (int)(v.x >> SHIFT);
        int pos = s0 + atomicAdd(&cnt[loc], 1);
        S[pos] = make_int2((int)(v.x & NMASK), (int)v.y);
    }
}

// ---------------- aggregate: wave per row, bf16 gather, unroll x4 ----------------
// Fixed-point int32 accumulation (scale 2^21): integer sums are order-invariant,
// so the racy storage order upstream cannot change the output bit pattern
// between calls. Bounds: |emb| <= ~0.02, weighted degree <= ~300 ->
// |iacc| < 2^24, |ideg| < 2^30; per-term quantization 2^-21 (below bf16 LSB).
__global__ __launch_bounds__(256) void agg_kernel(
    const int2* __restrict__ sorted, const int* __restrict__ off,
    const unsigned short* __restrict__ nbremb_bf, unsigned short* __restrict__ msg_bf)
{
    const float SCL  = 2097152.0f;          // 2^21
    const float ISCL = 1.0f / 2097152.0f;
    int wave = threadIdx.x >> 6;
    int lane = threadIdx.x & 63;
    int row = blockIdx.x * 4 + wave;   // grid sized exactly
    int start = off[row];
    int end   = off[row + 1];
    int iacc0 = 0, iacc1 = 0, ideg = 0;
    int j = start;
    for (; j + 4 <= end; j += 4) {
        int2 v0 = sorted[j];
        int2 v1 = sorted[j + 1];
        int2 v2 = sorted[j + 2];
        int2 v3 = sorted[j + 3];
        unsigned pk0 = *(const unsigned*)(nbremb_bf + (size_t)v0.x * DIM + 2 * lane);
        unsigned pk1 = *(const unsigned*)(nbremb_bf + (size_t)v1.x * DIM + 2 * lane);
        unsigned pk2 = *(const unsigned*)(nbremb_bf + (size_t)v2.x * DIM + 2 * lane);
        unsigned pk3 = *(const unsigned*)(nbremb_bf + (size_t)v3.x * DIM + 2 * lane);
        float w0 = __int_as_float(v0.y), w1 = __int_as_float(v1.y);
        float w2 = __int_as_float(v2.y), w3 = __int_as_float(v3.y);
        ideg  += (int)(w0 * SCL) + (int)(w1 * SCL) + (int)(w2 * SCL) + (int)(w3 * SCL);
        iacc0 += (int)(w0 * bf2f(pk0 & 0xFFFFu) * SCL) + (int)(w1 * bf2f(pk1 & 0xFFFFu) * SCL)
               + (int)(w2 * bf2f(pk2 & 0xFFFFu) * SCL) + (int)(w3 * bf2f(pk3 & 0xFFFFu) * SCL);
        iacc1 += (int)(w0 * bf2f(pk0 >> 16) * SCL) + (int)(w1 * bf2f(pk1 >> 16) * SCL)
               + (int)(w2 * bf2f(pk2 >> 16) * SCL) + (int)(w3 * bf2f(pk3 >> 16) * SCL);
    }
    for (; j < end; ++j) {
        int2 v = sorted[j];
        float w = __int_as_float(v.y);
        unsigned pk = *(const unsigned*)(nbremb_bf + (size_t)v.x * DIM + 2 * lane);
        ideg  += (int)(w * SCL);
        iacc0 += (int)(w * bf2f(pk & 0xFFFFu) * SCL);
        iacc1 += (int)(w * bf2f(pk >> 16) * SCL);
    }
    float deg = (float)ideg * ISCL;
    float inv = 1.0f / (deg + 1e-8f);
    float a0 = (float)iacc0 * ISCL;
    float a1 = (float)iacc1 * ISCL;
    unsigned o = f2bf(a0 * inv) | (f2bf(a1 * inv) << 16);
    *(unsigned*)(msg_bf + (size_t)row * DIM + 2 * lane) = o;
}

// ---------------- MFMA MLP: swapped-operand, wave per 16 rows ----------------
// NOTE: the 32-row variant failed the harness determinism check 3/3 times
// (R8/R9/R15) while this 16-row variant passed (R7/R10/R14/R16). Frozen.
#define HP 136   // hs row pitch in bf16
__global__ __launch_bounds__(256) void mlp_mfma_kernel(
    const unsigned short* __restrict__ embbf, const unsigned short* __restrict__ msgbf,
    const unsigned short* __restrict__ w1pk, const unsigned short* __restrict__ w2pk,
    const float* __restrict__ b1, const float* __restrict__ g1, const float* __restrict__ be1,
    const float* __restrict__ b2, const float* __restrict__ g2, const float* __restrict__ be2,
    float* __restrict__ out, int nrows)
{
    __shared__ __align__(16) unsigned short hs_all[4][16 * HP];
    int t = threadIdx.x;
    int wave = t >> 6, lane = t & 63;
    int tile = blockIdx.x * 4 + wave;
    if (tile * 16 >= nrows) return;          // padding waves only; no barriers used
    int r16 = lane & 15;
    int hi  = lane >> 4;
    int row = tile * 16 + r16;
    unsigned short* hs = hs_all[wave];

    // ---- layer 1: 8 mt x 8 ks MFMAs ----
    f32x4 acc[8];
    #pragma unroll
    for (int mt = 0; mt < 8; ++mt) {
        float4 bb = *(const float4*)&b1[mt * 16 + hi * 4];
        acc[mt] = (f32x4){bb.x, bb.y, bb.z, bb.w};
    }
    const unsigned short* x0 = embbf + (size_t)row * DIM;
    const unsigned short* x1 = msgbf + (size_t)row * DIM;
    #pragma unroll
    for (int ks = 0; ks < 8; ++ks) {
        const unsigned short* xs = (ks < 4) ? (x0 + ks * 32 + hi * 8)
                                            : (x1 + (ks - 4) * 32 + hi * 8);
        short8v bfrag = *(const short8v*)xs;
        #pragma unroll
        for (int mt = 0; mt < 8; ++mt) {
            short8v afrag = *(const short8v*)(w1pk + (((mt * 8 + ks) * 64 + lane) << 3));
            acc[mt] = __builtin_amdgcn_mfma_f32_16x16x32_bf16(afrag, bfrag, acc[mt], 0, 0, 0);
        }
    }

    // ---- LN1 + ReLU -> hs (bf16) ----
    float s = 0.f, q = 0.f;
    #pragma unroll
    for (int mt = 0; mt < 8; ++mt) {
        #pragma unroll
        for (int r = 0; r < 4; ++r) { float v = acc[mt][r]; s += v; q += v * v; }
    }
    s += __shfl_xor(s, 16); s += __shfl_xor(s, 32);
    q += __shfl_xor(q, 16); q += __shfl_xor(q, 32);
    float mu = s * (1.0f / 128.0f);
    float var = q * (1.0f / 128.0f) - mu * mu;
    float rstd = rsqrtf(var + 1e-5f);
    #pragma unroll
    for (int mt = 0; mt < 8; ++mt) {
        float4 gg = *(const float4*)&g1[mt * 16 + hi * 4];
        float4 bb = *(const float4*)&be1[mt * 16 + hi * 4];
        float h0 = fmaxf((acc[mt][0] - mu) * rstd * gg.x + bb.x, 0.f);
        float h1 = fmaxf((acc[mt][1] - mu) * rstd * gg.y + bb.y, 0.f);
        float h2 = fmaxf((acc[mt][2] - mu) * rstd * gg.z + bb.z, 0.f);
        float h3 = fmaxf((acc[mt][3] - mu) * rstd * gg.w + bb.w, 0.f);
        uint2 pk = make_uint2(f2bf(h0) | (f2bf(h1) << 16), f2bf(h2) | (f2bf(h3) << 16));
        *(uint2*)&hs[r16 * HP + mt * 16 + hi * 4] = pk;
    }

    // ---- layer 2: 4 mt x 4 ks MFMAs ----
    f32x4 acc2[4];
    #pragma unroll
    for (int mt = 0; mt < 4; ++mt) {
        float4 bb = *(const float4*)&b2[mt * 16 + hi * 4];
        acc2[mt] = (f32x4){bb.x, bb.y, bb.z, bb.w};
    }
    #pragma unroll
    for (int ks = 0; ks < 4; ++ks) {
        short8v bfrag = *(const short8v*)&hs[r16 * HP + ks * 32 + hi * 8];
        #pragma unroll
        for (int mt = 0; mt < 4; ++mt) {
            short8v afrag = *(const short8v*)(w2pk + (((mt * 4 + ks) * 64 + lane) << 3));
            acc2[mt] = __builtin_amdgcn_mfma_f32_16x16x32_bf16(afrag, bfrag, acc2[mt], 0, 0, 0);
        }
    }

    // ---- LN2 -> out ----
    float s2 = 0.f, q2 = 0.f;
    #pragma unroll
    for (int mt = 0; mt < 4; ++mt) {
        #pragma unroll
        for (int r = 0; r < 4; ++r) { float v = acc2[mt][r]; s2 += v; q2 += v * v; }
    }
    s2 += __shfl_xor(s2, 16); s2 += __shfl_xor(s2, 32);
    q2 += __shfl_xor(q2, 16); q2 += __shfl_xor(q2, 32);
    float mu2 = s2 * (1.0f / 64.0f);
    float var2 = q2 * (1.0f / 64.0f) - mu2 * mu2;
    float rstd2 = rsqrtf(var2 + 1e-5f);
    #pragma unroll
    for (int mt = 0; mt < 4; ++mt) {
        float4 gg = *(const float4*)&g2[mt * 16 + hi * 4];
        float4 bb = *(const float4*)&be2[mt * 16 + hi * 4];
        float4 o;
        o.x = (acc2[mt][0] - mu2) * rstd2 * gg.x + bb.x;
        o.y = (acc2[mt][1] - mu2) * rstd2 * gg.y + bb.y;
        o.z = (acc2[mt][2] - mu2) * rstd2 * gg.z + bb.z;
        o.w = (acc2[mt][3] - mu2) * rstd2 * gg.w + bb.w;
        *(float4*)&out[(size_t)row * OUTD + mt * 16 + hi * 4] = o;
    }
}

extern "C" void kernel_launch(void* const* d_in, const int* in_sizes, int n_in,
                              void* d_out, int out_size, void* d_ws, size_t ws_size,
                              hipStream_t stream) {
    const int*   ep   = (const int*)d_in[0];
    const int*   ec   = (const int*)d_in[1];
    const float* ew   = (const float*)d_in[2];
    const float* pemb = (const float*)d_in[3];
    const float* cemb = (const float*)d_in[4];
    const float* w1p  = (const float*)d_in[5];
    const float* b1p  = (const float*)d_in[6];
    const float* g1p  = (const float*)d_in[7];
    const float* be1p = (const float*)d_in[8];
    const float* w2p  = (const float*)d_in[9];
    const float* b2p  = (const float*)d_in[10];
    const float* g2p  = (const float*)d_in[11];
    const float* be2p = (const float*)d_in[12];
    const float* w1c  = (const float*)d_in[13];
    const float* b1c  = (const float*)d_in[14];
    const float* g1c  = (const float*)d_in[15];
    const float* be1c = (const float*)d_in[16];
    const float* w2c  = (const float*)d_in[17];
    const float* b2c  = (const float*)d_in[18];
    const float* g2c  = (const float*)d_in[19];
    const float* be2c = (const float*)d_in[20];

    // ---- meta workspace (ints) ----
    int* wsi  = (int*)d_ws;
    int* PH   = wsi;               // [98*16]  zeroed every call
    int* CH   = PH + 1568;         // [79*16]  zeroed every call
    int* PCUR = CH + 1264;         // [98*16]  (written by bscan)
    int* CCUR = PCUR + 1568;       // [79*16]
    int* POFF = CCUR + 1264;       // [100]
    int* COFF = POFF + 100;        // [84]
    int* rowoff_p = COFF + 84;         // [100004]
    int* rowoff_c = rowoff_p + 100004; // [20004]
    const int zero_ints = 1568 + 1264;                                      // 2832
    const int meta_ints = 2832 + 1568 + 1264 + 100 + 84 + 100004 + 20004;   // 125856

    // ---- big regions (stream-ordered lifetimes; aliases noted) ----
    char* big = (char*)(wsi + meta_ints);
    uint2* Ap = (uint2*)big;                             // 16 MB  (part out, bsort_p in)
    int2*  Sp = (int2*)(big + 16000000);                 // 16 MB  (bsort_p out, agg_p in)
    char*  zoneC = big + 32000000;                       // 30.72 MB zone
    uint2* Ac = (uint2*)zoneC;                           //   16 MB (part out, bsort_c in)
    int2*  Sc = (int2*)Ap;                               //   aliases Ap (dead after bsort_p)
    unsigned short* pmsgb = (unsigned short*)zoneC;                   // 25.6 MB (after bsort_c)
    unsigned short* cmsgb = (unsigned short*)(zoneC + 25600000);      // 5.12 MB
    unsigned short* pembbf = (unsigned short*)(zoneC + 30720000);     // 25.6 MB
    unsigned short* cembbf = pembbf + (size_t)NP * DIM;               // 5.12 MB
    unsigned short* w1pk_p = cembbf + (size_t)NC * DIM;  // 64 KB
    unsigned short* w2pk_p = w1pk_p + 32768;             // 16 KB
    unsigned short* w1pk_c = w2pk_p + 8192;              // 64 KB
    unsigned short* w2pk_c = w1pk_c + 32768;             // 16 KB

    zero4_kernel<<<3, 256, 0, stream>>>((float4*)wsi, (size_t)zero_ints / 4);

    // bf16 conversions + weight prepack (independent of edge pipeline)
    conv_kernel<<<2048, 256, 0, stream>>>((const float4*)pemb, (uint2*)pembbf,
                                          (size_t)NP * DIM / 4);
    conv_kernel<<<640, 256, 0, stream>>>((const float4*)cemb, (uint2*)cembbf,
                                         (size_t)NC * DIM / 4);
    pack_kernel<<<40, 256, 0, stream>>>(w1p, w2p, w1c, w2c,
                                        w1pk_p, w2pk_p, w1pk_c, w2pk_c);

    bhist_kernel<<<256, 256, 0, stream>>>(ep, ec, PH, CH);
    bscan_kernel<<<1, 256, 0, stream>>>(PH, CH, POFF, COFF, PCUR, CCUR);

    int pblocks = (NE + CHUNK - 1) / CHUNK;   // 489
    part_kernel<<<pblocks, 256, 0, stream>>>(ep, ec, ew, PCUR, CCUR, Ap, Ac);

    bsort_kernel<1024, 15, 0x7FFFu><<<PBK, 256, 0, stream>>>(Ap, POFF, Sp, rowoff_p, NP, PBK);
    bsort_kernel<256, 17, 0x1FFFFu><<<CBK, 256, 0, stream>>>(Ac, COFF, Sc, rowoff_c, NC, CBK);

    agg_kernel<<<NP / 4, 256, 0, stream>>>(Sp, rowoff_p, cembbf, pmsgb);
    agg_kernel<<<NC / 4, 256, 0, stream>>>(Sc, rowoff_c, pembbf, cmsgb);

    float* out_p = (float*)d_out;             // [NP, 64]
    float* out_c = out_p + (size_t)NP * OUTD; // [NC, 64]

    mlp_mfma_kernel<<<(NP / 16 + 3) / 4, 256, 0, stream>>>(
        pembbf, pmsgb, w1pk_p, w2pk_p,
        b1p, g1p, be1p, b2p, g2p, be2p, out_p, NP);
    mlp_mfma_kernel<<<(NC / 16 + 3) / 4, 256, 0, stream>>>(
        cembbf, cmsgb, w1pk_c, w2pk_c,
        b1c, g1c, be1c, b2c, g2c, be2c, out_c, NC);
}